// Round 4
// baseline (72.371 us; speedup 1.0000x reference)
//
#include <hip/hip_runtime.h>
#include <cstddef>

namespace {

constexpr int B  = 32;
constexpr int NB = 688;
constexpr int K  = 4;
constexpr int L  = 688;
constexpr int S  = 688;
constexpr int V  = 50;
constexpr int LS = L + S;            // 1376
constexpr int ROWS = B * NB;         // 22016 (== B*S tag rows)
constexpr float TINV = 10.0f;        // 1 / TEMP
constexpr int Q3 = S / 4 - 128;      // 44: lanes with a valid 3rd quad
constexpr int QR = S / 4;            // 172 float4 per row

constexpr int NBLK  = 1024;          // 4 blocks/CU exactly (4 waves/SIMD)
constexpr int NWAVE = NBLK * 4;      // 4096 waves

// ws: 9 float arrays of [NWAVE]
constexpr int A_PT = 0, A_PH = 1, A_RS = 2, A_RV = 3, A_CS = 4,
              A_CV = 5, A_TS = 6, A_TC = 7, A_ES = 8;

__device__ __forceinline__ float wred_sum(float v) {
#pragma unroll
  for (int o = 32; o > 0; o >>= 1) v += __shfl_xor(v, o);
  return v;
}
__device__ __forceinline__ void wred2(float& a, float& b) {
#pragma unroll
  for (int o = 32; o > 0; o >>= 1) { a += __shfl_xor(a, o); b += __shfl_xor(b, o); }
}
__device__ __forceinline__ void wred4(float& a, float& b, float& c, float& d) {
#pragma unroll
  for (int o = 32; o > 0; o >>= 1) {
    a += __shfl_xor(a, o); b += __shfl_xor(b, o);
    c += __shfl_xor(c, o); d += __shfl_xor(d, o);
  }
}

__device__ __forceinline__ float4 q_exp_t(const float4 v) {
  return make_float4(__expf(v.x * TINV), __expf(v.y * TINV),
                     __expf(v.z * TINV), __expf(v.w * TINV));
}
__device__ __forceinline__ float q_sum(const float4 a) {
  return (a.x + a.y) + (a.z + a.w);
}

__device__ __forceinline__ void load3(const float4* __restrict__ p4, int lane,
                                      bool t3, float4& a, float4& b, float4& c) {
  a = p4[lane];
  b = p4[lane + 64];
  c = t3 ? p4[lane + 128] : make_float4(0.f, 0.f, 0.f, 0.f);
}

// pass-2 quad: csum += sum(c); for c>=0: wsum += c*(log(e+A)-lgz)
__device__ __forceinline__ void c_quad(const float4 e, const float4 c,
                                       float A, float lgz,
                                       float& wsum, float& csum, bool& anyv) {
  csum += ((c.x + c.y) + (c.z + c.w));
  if (c.x >= 0.f) { wsum += c.x * (__logf(e.x + A) - lgz); anyv = true; }
  if (c.y >= 0.f) { wsum += c.y * (__logf(e.y + A) - lgz); anyv = true; }
  if (c.z >= 0.f) { wsum += c.z * (__logf(e.z + A) - lgz); anyv = true; }
  if (c.w >= 0.f) { wsum += c.w * (__logf(e.w + A) - lgz); anyv = true; }
}

// ---------------- pointer loss row ----------------
__device__ __forceinline__ void ptr_row(int r, int lane, bool t3,
    const float* __restrict__ plog, const int* __restrict__ box,
    const int* __restrict__ dmask, float& a0, float& a1)
{
  const float*  pl  = plog + (size_t)r * S;
  const float4* pl4 = reinterpret_cast<const float4*>(pl);
  float4 v0, v1, v2;
  load3(pl4, lane, t3, v0, v1, v2);
  int idx = (lane < K) ? box[(size_t)r * K + lane] : -1;

  float4 e0 = q_exp_t(v0);
  float4 e1 = q_exp_t(v1);
  float4 e2 = t3 ? q_exp_t(v2) : make_float4(0.f, 0.f, 0.f, 0.f);
  float z = q_sum(e0) + q_sum(e1) + q_sum(e2);
  z = wred_sum(z);
  float lse = __logf(z);

  bool vld = (idx != -1) & (lane < K);
  float g = 0.f;
  if (vld) {
    int bb = r / NB;
    int vp = dmask[(size_t)bb * LS + L + idx];
    float sv = pl[idx] * TINV;           // row is L1-resident
    g = vp ? (sv - lse) : -INFINITY;
  }
  g += __shfl_xor(g, 1);                 // sum over lanes 0..3
  g += __shfl_xor(g, 2);
  unsigned long long bal = __ballot(vld);
  int cnt = __popcll(bal);
  if (cnt > 0) {
    a0 += -(g / (float)cnt);             // only lane 0's value is consumed
    a1 += 1.f;
  }
}

// ---------------- tag loss row ----------------
__device__ __forceinline__ void tag_row(int row, int lane,
    const float* __restrict__ tl_base, const int* __restrict__ tgt,
    float& a0, float& a1)
{
  const float* tl = tl_base + (size_t)row * V;
  const bool a = (lane < V);
  float xv = a ? tl[lane] : 0.f;
  int   t  = tgt[row];                   // broadcast load
  float ev = a ? __expf(xv) : 0.f;
  float sx = a ? xv : 0.f;
  wred2(ev, sx);
  float lse = __logf(ev);
  float xt  = __shfl(xv, t);             // t in [0,50)
  if (t != 0) {                          // PAD == 0
    a0 += lse - 0.9f * xt - 0.002f * sx; // SM=0.1, mean = sumx/50
    a1 += 1.f;
  }
}

// ---------------- empty BCE (one batch per call) ----------------
__device__ __forceinline__ void empty_row(int b, int lane,
    const float* __restrict__ elog, const int* __restrict__ dmask,
    const int* __restrict__ emask, float& a0)
{
  const float* el = elog + (size_t)b * S;
  const int* dm = dmask + (size_t)b * LS + L;
  const int* em = emask + (size_t)b * LS + L;
  float bs = 0.f, bc = 0.f;
  for (int j = lane; j < S; j += 64) {
    float xv = el[j];
    int d = dm[j], e = em[j];
    float tt = (float)e;
    float bce = fmaxf(xv, 0.f) - xv * tt + log1pf(__expf(-fabsf(xv)));
    if (d | e) { bs += bce; bc += 1.f; }
  }
  wred2(bs, bc);
  a0 += bs / (bc + 1e-8f);
}

__global__ __launch_bounds__(256, 4) void fused_loss(
    const float* __restrict__ tag_logits, const int* __restrict__ tag_targets,
    const float* __restrict__ plog, const int* __restrict__ box,
    const int* __restrict__ dmask, const int* __restrict__ emask,
    const float* __restrict__ elog,
    const float* __restrict__ rsim, const float* __restrict__ csim,
    const float* __restrict__ rcoef, const float* __restrict__ ccoef,
    float* __restrict__ ws)
{
  const int tid  = threadIdx.x;
  const int lane = tid & 63;
  const int wave = tid >> 6;
  const int wid  = blockIdx.x * 4 + wave;
  const bool t3  = (lane < Q3);

  // contiguous per-wave slice of rows (5 or 6 rows): [ws_, we_)
  const int ws_ = (wid * 43) >> 3;          // wid * 22016 / 4096
  const int we_ = ((wid + 1) * 43) >> 3;

  float aPT = 0.f, aPH = 0.f, aRS = 0.f, aRV = 0.f, aCS = 0.f,
        aCV = 0.f, aTS = 0.f, aTC = 0.f, aES = 0.f;

  // ============ contrastive phase: software-pipelined row pairs ============
  {
    float4 nr0, nr1, nr2, nm0, nm1, nm2;      // next rsim / csim row (prefetch)
    int r = ws_;
    if (r < we_) {
      load3(reinterpret_cast<const float4*>(rsim) + (size_t)r * QR, lane, t3, nr0, nr1, nr2);
      load3(reinterpret_cast<const float4*>(csim) + (size_t)r * QR, lane, t3, nm0, nm1, nm2);
    }
    while (r < we_) {
      // current <- prefetched
      float4 x0 = nr0, x1 = nr1, x2 = nr2;
      float4 y0 = nm0, y1 = nm1, y2 = nm2;
      // coef loads for current row (consumed after z-reduce: latency hidden)
      float4 cr0, cr1, cr2, cm0, cm1, cm2;
      load3(reinterpret_cast<const float4*>(rcoef) + (size_t)r * QR, lane, t3, cr0, cr1, cr2);
      load3(reinterpret_cast<const float4*>(ccoef) + (size_t)r * QR, lane, t3, cm0, cm1, cm2);
      // prefetch next row's sims (consumed next iteration)
      const int rn = r + 1;
      if (rn < we_) {
        load3(reinterpret_cast<const float4*>(rsim) + (size_t)rn * QR, lane, t3, nr0, nr1, nr2);
        load3(reinterpret_cast<const float4*>(csim) + (size_t)rn * QR, lane, t3, nm0, nm1, nm2);
      }
      // exp (in place: x/y become e-values)
      x0 = q_exp_t(x0); x1 = q_exp_t(x1);
      x2 = t3 ? q_exp_t(x2) : make_float4(0.f, 0.f, 0.f, 0.f);
      y0 = q_exp_t(y0); y1 = q_exp_t(y1);
      y2 = t3 ? q_exp_t(y2) : make_float4(0.f, 0.f, 0.f, 0.f);

      float zr = q_sum(x0) + q_sum(x1) + q_sum(x2);
      float zc = q_sum(y0) + q_sum(y1) + q_sum(y2);
      wred2(zr, zc);                       // two interleaved DS chains
      const float Ar = 1e-8f * zr, lgzr = __logf(zr);
      const float Ac = 1e-8f * zc, lgzc = __logf(zc);

      float wr = 0.f, cr = 0.f, wc = 0.f, cc = 0.f;
      bool anyr = false, anyc = false;
      c_quad(x0, cr0, Ar, lgzr, wr, cr, anyr);
      c_quad(y0, cm0, Ac, lgzc, wc, cc, anyc);
      c_quad(x1, cr1, Ar, lgzr, wr, cr, anyr);
      c_quad(y1, cm1, Ac, lgzc, wc, cc, anyc);
      if (t3) {
        c_quad(x2, cr2, Ar, lgzr, wr, cr, anyr);
        c_quad(y2, cm2, Ac, lgzc, wc, cc, anyc);
      }
      wred4(wr, cr, wc, cc);               // four interleaved DS chains
      if (__ballot(anyr)) { aRS += -(wr / (cr + 1e-8f)); aRV += 1.f; }
      if (__ballot(anyc)) { aCS += -(wc / (cc + 1e-8f)); aCV += 1.f; }
      r = rn;
    }
  }

  // ============ pointer + tag phase ============
  for (int r = ws_; r < we_; ++r) {
    ptr_row(r, lane, t3, plog, box, dmask, aPT, aPH);
    tag_row(r, lane, tag_logits, tag_targets, aTS, aTC);
  }

  // ============ empty BCE: first 32 waves ============
  if (wid < B) empty_row(wid, lane, elog, dmask, emask, aES);

  if (lane == 0) {
    ws[A_PT * NWAVE + wid] = aPT;
    ws[A_PH * NWAVE + wid] = aPH;
    ws[A_RS * NWAVE + wid] = aRS;
    ws[A_RV * NWAVE + wid] = aRV;
    ws[A_CS * NWAVE + wid] = aCS;
    ws[A_CV * NWAVE + wid] = aCV;
    ws[A_TS * NWAVE + wid] = aTS;
    ws[A_TC * NWAVE + wid] = aTC;
    ws[A_ES * NWAVE + wid] = aES;
  }
}

__global__ __launch_bounds__(256) void combine_kernel(
    const float* __restrict__ ws, float* __restrict__ out)
{
  const int tid  = threadIdx.x;   // 256 threads
  const int lane = tid & 63;
  const int w    = tid >> 6;
  double acc[9];
#pragma unroll
  for (int a = 0; a < 9; ++a) acc[a] = 0.0;
  for (int i = tid; i < NWAVE; i += 256) {
#pragma unroll
    for (int a = 0; a < 9; ++a) acc[a] += (double)ws[a * NWAVE + i];
  }
#pragma unroll
  for (int a = 0; a < 9; ++a) {
#pragma unroll
    for (int o = 32; o > 0; o >>= 1) acc[a] += __shfl_xor(acc[a], o);
  }
  __shared__ double sh[4][9];
  if (lane == 0) {
#pragma unroll
    for (int a = 0; a < 9; ++a) sh[w][a] = acc[a];
  }
  __syncthreads();
  if (tid == 0) {
    double t[9];
#pragma unroll
    for (int a = 0; a < 9; ++a) t[a] = sh[0][a] + sh[1][a] + sh[2][a] + sh[3][a];
    float cls  = (float)(t[A_TS] / t[A_TC]);
    float ptr  = (float)(t[A_PT] / (t[A_PH] + 1e-6));
    float emp  = (float)(t[A_ES] / (double)B);
    float row  = (float)(t[A_RS] / (t[A_RV] + 1e-8));
    float col  = (float)(t[A_CS] / (t[A_CV] + 1e-8));
    float total = cls + ptr + emp + 0.5f * row + 0.5f * col;
    out[0] = total; out[1] = cls; out[2] = ptr;
    out[3] = emp;   out[4] = row; out[5] = col;
  }
}

} // anonymous namespace

extern "C" void kernel_launch(void* const* d_in, const int* in_sizes, int n_in,
                              void* d_out, int out_size, void* d_ws, size_t ws_size,
                              hipStream_t stream)
{
  const float* tag_logits  = (const float*)d_in[0];
  const int*   tag_targets = (const int*)  d_in[1];
  const float* plog        = (const float*)d_in[2];
  const int*   box         = (const int*)  d_in[3];
  const int*   dmask       = (const int*)  d_in[4];
  const int*   emask       = (const int*)  d_in[5];
  const float* elog        = (const float*)d_in[6];
  const float* rsim        = (const float*)d_in[7];
  const float* csim        = (const float*)d_in[8];
  const float* rcoef       = (const float*)d_in[9];
  const float* ccoef       = (const float*)d_in[10];

  float* ws  = (float*)d_ws;
  float* out = (float*)d_out;

  fused_loss<<<NBLK, 256, 0, stream>>>(tag_logits, tag_targets, plog, box,
                                       dmask, emask, elog, rsim, csim,
                                       rcoef, ccoef, ws);
  combine_kernel<<<1, 256, 0, stream>>>(ws, out);
}

// Round 5
// 67.059 us; speedup vs baseline: 1.0792x; 1.0792x over previous
//
#include <hip/hip_runtime.h>
#include <cstddef>

namespace {

constexpr int B  = 32;
constexpr int NB = 688;
constexpr int K  = 4;
constexpr int L  = 688;
constexpr int S  = 688;
constexpr int V  = 50;
constexpr int LS = L + S;            // 1376
constexpr float TINV = 10.0f;        // 1 / TEMP
constexpr float E10  = 14.4269504088896340736f;  // 10 * log2(e)
constexpr int Q3 = S / 4 - 128;      // 44: lanes with a valid 3rd quad
constexpr int QR = S / 4;            // 172 float4 per row

constexpr int NBLK  = 1024;          // 4 waves/block, contiguous row slices
constexpr int NWAVE = NBLK * 4;      // 4096 waves

typedef float f32x4 __attribute__((ext_vector_type(4)));

// ws: 9 float arrays of [NBLK] (per-block partials)
constexpr int A_PT = 0, A_PH = 1, A_RS = 2, A_RV = 3, A_CS = 4,
              A_CV = 5, A_TS = 6, A_TC = 7, A_ES = 8;

__device__ __forceinline__ f32x4 zero4() {
  f32x4 z = {0.f, 0.f, 0.f, 0.f};
  return z;
}
__device__ __forceinline__ void wred2(float& a, float& b) {
#pragma unroll
  for (int o = 32; o > 0; o >>= 1) { a += __shfl_xor(a, o); b += __shfl_xor(b, o); }
}
__device__ __forceinline__ void wred3(float& a, float& b, float& c) {
#pragma unroll
  for (int o = 32; o > 0; o >>= 1) {
    a += __shfl_xor(a, o); b += __shfl_xor(b, o); c += __shfl_xor(c, o);
  }
}
__device__ __forceinline__ void wred4(float& a, float& b, float& c, float& d) {
#pragma unroll
  for (int o = 32; o > 0; o >>= 1) {
    a += __shfl_xor(a, o); b += __shfl_xor(b, o);
    c += __shfl_xor(c, o); d += __shfl_xor(d, o);
  }
}

// exp(x * 10) = exp2(x * 10*log2e)  — single mul + v_exp_f32
__device__ __forceinline__ f32x4 q_exp10(const f32x4 v) {
  f32x4 r;
  r.x = exp2f(v.x * E10); r.y = exp2f(v.y * E10);
  r.z = exp2f(v.z * E10); r.w = exp2f(v.w * E10);
  return r;
}
__device__ __forceinline__ float q_sum(const f32x4 a) {
  return (a.x + a.y) + (a.z + a.w);
}

// non-temporal 3-quad row load (streaming, no cache allocation)
__device__ __forceinline__ void load3nt(const f32x4* __restrict__ p4, int lane,
                                        bool t3, f32x4& a, f32x4& b, f32x4& c) {
  a = __builtin_nontemporal_load(p4 + lane);
  b = __builtin_nontemporal_load(p4 + lane + 64);
  c = zero4();
  if (t3) c = __builtin_nontemporal_load(p4 + lane + 128);
}

// pass-2 quad: csum += sum(c); for c>=0: wsum += c*(log(e+A)-lgz)
__device__ __forceinline__ void c_quad(const f32x4 e, const f32x4 c,
                                       float A, float lgz,
                                       float& wsum, float& csum, bool& anyv) {
  csum += ((c.x + c.y) + (c.z + c.w));
  if (c.x >= 0.f) { wsum += c.x * (__logf(e.x + A) - lgz); anyv = true; }
  if (c.y >= 0.f) { wsum += c.y * (__logf(e.y + A) - lgz); anyv = true; }
  if (c.z >= 0.f) { wsum += c.z * (__logf(e.z + A) - lgz); anyv = true; }
  if (c.w >= 0.f) { wsum += c.w * (__logf(e.w + A) - lgz); anyv = true; }
}

// ---------------- empty BCE (one batch per call) ----------------
__device__ __forceinline__ void empty_row(int b, int lane,
    const float* __restrict__ elog, const int* __restrict__ dmask,
    const int* __restrict__ emask, float& a0)
{
  const float* el = elog + (size_t)b * S;
  const int* dm = dmask + (size_t)b * LS + L;
  const int* em = emask + (size_t)b * LS + L;
  float bs = 0.f, bc = 0.f;
  for (int j = lane; j < S; j += 64) {
    float xv = el[j];
    int d = dm[j], e = em[j];
    float tt = (float)e;
    float bce = fmaxf(xv, 0.f) - xv * tt + log1pf(__expf(-fabsf(xv)));
    if (d | e) { bs += bce; bc += 1.f; }
  }
  wred2(bs, bc);
  a0 += bs / (bc + 1e-8f);
}

__global__ __launch_bounds__(256, 4) void fused_loss(
    const float* __restrict__ tag_logits, const int* __restrict__ tag_targets,
    const float* __restrict__ plog, const int* __restrict__ box,
    const int* __restrict__ dmask, const int* __restrict__ emask,
    const float* __restrict__ elog,
    const float* __restrict__ rsim, const float* __restrict__ csim,
    const float* __restrict__ rcoef, const float* __restrict__ ccoef,
    float* __restrict__ ws)
{
  const int tid  = threadIdx.x;
  const int lane = tid & 63;
  const int wave = tid >> 6;
  const int wid  = blockIdx.x * 4 + wave;
  const bool t3  = (lane < Q3);

  // contiguous per-wave slice of rows (5 or 6): [ws_, we_)
  const int ws_ = (wid * 43) >> 3;          // wid * 22016 / 4096
  const int we_ = ((wid + 1) * 43) >> 3;

  float aPT = 0.f, aPH = 0.f, aRS = 0.f, aRV = 0.f, aCS = 0.f,
        aCV = 0.f, aTS = 0.f, aTC = 0.f, aES = 0.f;

  // ============ contrastive phase: software-pipelined row pairs, NT ============
  {
    f32x4 nr0, nr1, nr2, nm0, nm1, nm2;      // next rsim / csim row (prefetch)
    int r = ws_;
    if (r < we_) {
      load3nt(reinterpret_cast<const f32x4*>(rsim) + (size_t)r * QR, lane, t3, nr0, nr1, nr2);
      load3nt(reinterpret_cast<const f32x4*>(csim) + (size_t)r * QR, lane, t3, nm0, nm1, nm2);
    }
    while (r < we_) {
      f32x4 x0 = nr0, x1 = nr1, x2 = nr2;
      f32x4 y0 = nm0, y1 = nm1, y2 = nm2;
      // coef loads for current row (consumed after z-reduce: latency hidden)
      f32x4 cr0, cr1, cr2, cm0, cm1, cm2;
      load3nt(reinterpret_cast<const f32x4*>(rcoef) + (size_t)r * QR, lane, t3, cr0, cr1, cr2);
      load3nt(reinterpret_cast<const f32x4*>(ccoef) + (size_t)r * QR, lane, t3, cm0, cm1, cm2);
      // prefetch next row's sims
      const int rn = r + 1;
      if (rn < we_) {
        load3nt(reinterpret_cast<const f32x4*>(rsim) + (size_t)rn * QR, lane, t3, nr0, nr1, nr2);
        load3nt(reinterpret_cast<const f32x4*>(csim) + (size_t)rn * QR, lane, t3, nm0, nm1, nm2);
      }
      x0 = q_exp10(x0); x1 = q_exp10(x1);
      x2 = t3 ? q_exp10(x2) : zero4();
      y0 = q_exp10(y0); y1 = q_exp10(y1);
      y2 = t3 ? q_exp10(y2) : zero4();

      float zr = q_sum(x0) + q_sum(x1) + q_sum(x2);
      float zc = q_sum(y0) + q_sum(y1) + q_sum(y2);
      wred2(zr, zc);
      const float Ar = 1e-8f * zr, lgzr = __logf(zr);
      const float Ac = 1e-8f * zc, lgzc = __logf(zc);

      float wr = 0.f, cr = 0.f, wc = 0.f, cc = 0.f;
      bool anyr = false, anyc = false;
      c_quad(x0, cr0, Ar, lgzr, wr, cr, anyr);
      c_quad(y0, cm0, Ac, lgzc, wc, cc, anyc);
      c_quad(x1, cr1, Ar, lgzr, wr, cr, anyr);
      c_quad(y1, cm1, Ac, lgzc, wc, cc, anyc);
      if (t3) {
        c_quad(x2, cr2, Ar, lgzr, wr, cr, anyr);
        c_quad(y2, cm2, Ac, lgzc, wc, cc, anyc);
      }
      wred4(wr, cr, wc, cc);
      if (__ballot(anyr)) { aRS += -(wr / (cr + 1e-8f)); aRV += 1.f; }
      if (__ballot(anyc)) { aCS += -(wc / (cc + 1e-8f)); aCV += 1.f; }
      r = rn;
    }
  }

  // ============ pointer + tag phase: software-pipelined ============
  {
    f32x4 np0, np1, np2;
    float ntg; int nidx, ntt;
    int r = ws_;
    if (r < we_) {
      const f32x4* pl4 = reinterpret_cast<const f32x4*>(plog) + (size_t)r * QR;
      np0 = pl4[lane]; np1 = pl4[lane + 64];
      np2 = zero4(); if (t3) np2 = pl4[lane + 128];
      nidx = (lane < K) ? box[(size_t)r * K + lane] : -1;
      ntg  = (lane < V) ? tag_logits[(size_t)r * V + lane] : 0.f;
      ntt  = tag_targets[r];
    }
    while (r < we_) {
      f32x4 p0 = np0, p1 = np1, p2 = np2;
      float tg = ntg; int idx = nidx, tt = ntt;
      const int rn = r + 1;
      if (rn < we_) {
        const f32x4* pl4 = reinterpret_cast<const f32x4*>(plog) + (size_t)rn * QR;
        np0 = pl4[lane]; np1 = pl4[lane + 64];
        np2 = zero4(); if (t3) np2 = pl4[lane + 128];
        nidx = (lane < K) ? box[(size_t)rn * K + lane] : -1;
        ntg  = (lane < V) ? tag_logits[(size_t)rn * V + lane] : 0.f;
        ntt  = tag_targets[rn];
      }
      f32x4 e0 = q_exp10(p0), e1 = q_exp10(p1);
      f32x4 e2 = t3 ? q_exp10(p2) : zero4();
      float z  = q_sum(e0) + q_sum(e1) + q_sum(e2);
      float ev = (lane < V) ? __expf(tg) : 0.f;
      float sx = (lane < V) ? tg : 0.f;
      wred3(z, ev, sx);                     // ptr-z, tag-z, tag-sumx together
      float lse = __logf(z);

      bool vld = (idx != -1) & (lane < K);
      float g = 0.f;
      if (vld) {
        int bb = r / NB;
        int vp = dmask[(size_t)bb * LS + L + idx];
        float sv = plog[(size_t)r * S + idx] * TINV;   // L2-resident row
        g = vp ? (sv - lse) : -INFINITY;
      }
      g += __shfl_xor(g, 1);
      g += __shfl_xor(g, 2);
      int cnt = __popcll(__ballot(vld));
      if (cnt > 0) { aPT += -(g / (float)cnt); aPH += 1.f; }

      float tlse = __logf(ev);
      float xt   = __shfl(tg, tt);          // tt in [0,50)
      if (tt != 0) {                        // PAD == 0
        aTS += tlse - 0.9f * xt - 0.002f * sx;   // SM=0.1, mean = sumx/50
        aTC += 1.f;
      }
      r = rn;
    }
  }

  // ============ empty BCE: first 32 waves ============
  if (wid < B) empty_row(wid, lane, elog, dmask, emask, aES);

  // per-block partials
  __shared__ float sacc[4][9];
  if (lane == 0) {
    sacc[wave][0] = aPT; sacc[wave][1] = aPH; sacc[wave][2] = aRS;
    sacc[wave][3] = aRV; sacc[wave][4] = aCS; sacc[wave][5] = aCV;
    sacc[wave][6] = aTS; sacc[wave][7] = aTC; sacc[wave][8] = aES;
  }
  __syncthreads();
  if (tid < 9) {
    float t0 = sacc[0][tid] + sacc[1][tid] + sacc[2][tid] + sacc[3][tid];
    ws[tid * NBLK + blockIdx.x] = t0;
  }
}

__global__ __launch_bounds__(256) void combine_kernel(
    const float* __restrict__ ws, float* __restrict__ out)
{
  const int tid  = threadIdx.x;   // 256 threads
  const int lane = tid & 63;
  const int w    = tid >> 6;
  double acc[9];
#pragma unroll
  for (int a = 0; a < 9; ++a) acc[a] = 0.0;
  for (int i = tid; i < NBLK; i += 256) {
#pragma unroll
    for (int a = 0; a < 9; ++a) acc[a] += (double)ws[a * NBLK + i];
  }
#pragma unroll
  for (int a = 0; a < 9; ++a) {
#pragma unroll
    for (int o = 32; o > 0; o >>= 1) acc[a] += __shfl_xor(acc[a], o);
  }
  __shared__ double sh[4][9];
  if (lane == 0) {
#pragma unroll
    for (int a = 0; a < 9; ++a) sh[w][a] = acc[a];
  }
  __syncthreads();
  if (tid == 0) {
    double t[9];
#pragma unroll
    for (int a = 0; a < 9; ++a) t[a] = sh[0][a] + sh[1][a] + sh[2][a] + sh[3][a];
    float cls  = (float)(t[A_TS] / t[A_TC]);
    float ptr  = (float)(t[A_PT] / (t[A_PH] + 1e-6));
    float emp  = (float)(t[A_ES] / (double)B);
    float row  = (float)(t[A_RS] / (t[A_RV] + 1e-8));
    float col  = (float)(t[A_CS] / (t[A_CV] + 1e-8));
    float total = cls + ptr + emp + 0.5f * row + 0.5f * col;
    out[0] = total; out[1] = cls; out[2] = ptr;
    out[3] = emp;   out[4] = row; out[5] = col;
  }
}

} // anonymous namespace

extern "C" void kernel_launch(void* const* d_in, const int* in_sizes, int n_in,
                              void* d_out, int out_size, void* d_ws, size_t ws_size,
                              hipStream_t stream)
{
  const float* tag_logits  = (const float*)d_in[0];
  const int*   tag_targets = (const int*)  d_in[1];
  const float* plog        = (const float*)d_in[2];
  const int*   box         = (const int*)  d_in[3];
  const int*   dmask       = (const int*)  d_in[4];
  const int*   emask       = (const int*)  d_in[5];
  const float* elog        = (const float*)d_in[6];
  const float* rsim        = (const float*)d_in[7];
  const float* csim        = (const float*)d_in[8];
  const float* rcoef       = (const float*)d_in[9];
  const float* ccoef       = (const float*)d_in[10];

  float* ws  = (float*)d_ws;
  float* out = (float*)d_out;

  fused_loss<<<NBLK, 256, 0, stream>>>(tag_logits, tag_targets, plog, box,
                                       dmask, emask, elog, rsim, csim,
                                       rcoef, ccoef, ws);
  combine_kernel<<<1, 256, 0, stream>>>(ws, out);
}